// Round 12
// baseline (527.961 us; speedup 1.0000x reference)
//
#include <hip/hip_runtime.h>
#include <stdint.h>

#define NS 4096
#define DIM 2048
#define MARGINF 0.3f

typedef __bf16 bf16x8 __attribute__((ext_vector_type(8)));
typedef float floatx4 __attribute__((ext_vector_type(4)));
typedef unsigned long long u64;

// ---------------- fused Gram GEMM + prep + mining, 128x64 tiles, 1056 blocks -------
// fp32 is staged straight from X: buffer_load -> VGPR -> bf16 cvt -> ds_write.
// Loads for iter k+1 are issued BEFORE compute of iter k, so the vmcnt wait (at the
// next write phase) has a full compute phase in flight. Per-row sq accumulated in
// registers during cvt (identical thread/order map for A and B roles -> sq values
// bit-identical across blocks -> mining tie-breaks consistent).
#define BM 128
#define BCN 64
#define BKE 64            // K elems per staged chunk
#define NKCH (DIM / BKE)
#define NBLK 1056

// tile id -> (ry, cx); cum(y) = y*(65-y) tiles precede row-chunk y; XCD swizzle 8x132
__device__ __forceinline__ void tile_decode(int tt, int& ry, int& cx) {
  const int t = (tt & 7) * 132 + (tt >> 3);
  int y = (int)((65.0f - sqrtf((float)(4225 - 4 * t))) * 0.5f);
  while ((y + 1) * (64 - y) <= t) ++y;   // cum(y+1) = (y+1)*(64-y)
  while (y * (65 - y) > t) --y;
  ry = y;
  cx = 2 * y + (t - y * (65 - y));
}

__global__ __launch_bounds__(256, 4) void gemm_mine_kernel(
    const float* __restrict__ X, const int* __restrict__ targets,
    u64* __restrict__ posP, u64* __restrict__ negP) {
  int ry, cx;
  tile_decode(blockIdx.x, ry, cx);
  const int r0 = ry * BM;
  const int c0 = cx * BCN;

  __shared__ __align__(16) unsigned short Ab[BM * BKE];   // 16 KB bf16
  __shared__ __align__(16) unsigned short Bb[BCN * BKE];  //  8 KB bf16
  __shared__ float sqA[BM];
  __shared__ float sqB[BCN];

  const int tid = threadIdx.x;
  const int lane = tid & 63;
  const int w = tid >> 6;          // wave 0..3
  const int quad = lane >> 4;
  const int ml = lane & 15;
  const int sx = ml & 7;

  floatx4 acc[2][4];
#pragma unroll
  for (int i = 0; i < 2; ++i)
#pragma unroll
    for (int j = 0; j < 4; ++j)
#pragma unroll
      for (int k = 0; k < 4; ++k) acc[i][j][k] = 0.f;

  // staging map: 8 threads per row; thread covers row (s*32 + 8w + lane>>3) and
  // fp32 cols chk*8..+7 (two float4). bf16 LDS layout = proven XOR-swizzle:
  // 16B chunk chk of row R at slot chk^(R&7); here R&7 == (lane>>3)&7 for all
  // steps, so slot is per-thread constant. Writes: quarter-wave = 2 rows x 8
  // slots = 2-way = free (same pattern as the verified read side).
  const int srow = 8 * w + (lane >> 3);   // 0..31
  const int chk = lane & 7;
  const int slot = chk ^ ((lane >> 3) & 7);
  const float* pA = X + (size_t)(r0 + srow) * DIM + chk * 8;
  const float* pB = X + (size_t)(c0 + srow) * DIM + chk * 8;
  unsigned short* wA = Ab + srow * BKE + slot * 8;   // + s*32*BKE per step
  unsigned short* wB = Bb + srow * BKE + slot * 8;

  float4 rA[4][2], rB[2][2];
  float sqa[4] = {0.f, 0.f, 0.f, 0.f};
  float sqb[2] = {0.f, 0.f};

#define LOADS(K0)                                                              \
  {                                                                            \
    _Pragma("unroll") for (int s = 0; s < 4; ++s) {                            \
      rA[s][0] = *(const float4*)(pA + (size_t)(s * 32) * DIM + (K0));         \
      rA[s][1] = *(const float4*)(pA + (size_t)(s * 32) * DIM + (K0) + 4);     \
    }                                                                          \
    _Pragma("unroll") for (int s = 0; s < 2; ++s) {                            \
      rB[s][0] = *(const float4*)(pB + (size_t)(s * 32) * DIM + (K0));         \
      rB[s][1] = *(const float4*)(pB + (size_t)(s * 32) * DIM + (K0) + 4);     \
    }                                                                          \
  }

  LOADS(0);
  for (int it = 0; it < NKCH; ++it) {
    __syncthreads();   // iter-(k-1) LDS consumers done
    // cvt + sq + ds_write (vmcnt waits here had a full compute phase in flight)
#pragma unroll
    for (int s = 0; s < 4; ++s) {
      const float f[8] = {rA[s][0].x, rA[s][0].y, rA[s][0].z, rA[s][0].w,
                          rA[s][1].x, rA[s][1].y, rA[s][1].z, rA[s][1].w};
      bf16x8 v;
#pragma unroll
      for (int e = 0; e < 8; ++e) {
        v[e] = (__bf16)f[e];
        sqa[s] += f[e] * f[e];
      }
      *(bf16x8*)(wA + s * 32 * BKE) = v;
    }
#pragma unroll
    for (int s = 0; s < 2; ++s) {
      const float f[8] = {rB[s][0].x, rB[s][0].y, rB[s][0].z, rB[s][0].w,
                          rB[s][1].x, rB[s][1].y, rB[s][1].z, rB[s][1].w};
      bf16x8 v;
#pragma unroll
      for (int e = 0; e < 8; ++e) {
        v[e] = (__bf16)f[e];
        sqb[s] += f[e] * f[e];
      }
      *(bf16x8*)(wB + s * 32 * BKE) = v;
    }
    __syncthreads();   // staging visible
    if (it + 1 < NKCH) LOADS((it + 1) * BKE);   // in flight across compute
#pragma unroll
    for (int h = 0; h < 2; ++h) {
      const int sl = ((h << 2) + quad) ^ sx;
      bf16x8 af[2], bfr[4];
#pragma unroll
      for (int i = 0; i < 2; ++i)
        af[i] = *(const bf16x8*)(Ab + (w * 32 + i * 16 + ml) * BKE + sl * 8);
#pragma unroll
      for (int j = 0; j < 4; ++j)
        bfr[j] = *(const bf16x8*)(Bb + (j * 16 + ml) * BKE + sl * 8);
#pragma unroll
      for (int i = 0; i < 2; ++i)
#pragma unroll
        for (int j = 0; j < 4; ++j)
          acc[i][j] = __builtin_amdgcn_mfma_f32_16x16x32_bf16(af[i], bfr[j], acc[i][j], 0, 0, 0);
    }
  }

  // reduce per-row sq across the 8 staging threads (lanes differing in bits 0..2)
#pragma unroll
  for (int s = 0; s < 4; ++s) {
    float v = sqa[s];
    v += __shfl_xor(v, 1, 64);
    v += __shfl_xor(v, 2, 64);
    v += __shfl_xor(v, 4, 64);
    if (chk == 0) sqA[s * 32 + srow] = v;
  }
#pragma unroll
  for (int s = 0; s < 2; ++s) {
    float v = sqb[s];
    v += __shfl_xor(v, 1, 64);
    v += __shfl_xor(v, 2, 64);
    v += __shfl_xor(v, 4, 64);
    if (chk == 0) sqB[s * 32 + srow] = v;
  }
  __syncthreads();

  // epilogue A: row-direction mining. C/D layout: col = lane&15, row = quad*4+reg.
  const int cl = ml;
#pragma unroll
  for (int i = 0; i < 2; ++i) {
#pragma unroll
    for (int rg = 0; rg < 4; ++rg) {
      const int lr = w * 32 + i * 16 + quad * 4 + rg;
      const int gr = r0 + lr;
      const int tgt_r = targets[gr];
      const float sqr = sqA[lr];
      u64 pm = 0ULL;
      u64 nm = ~0ULL;
#pragma unroll
      for (int j = 0; j < 4; ++j) {
        const int lc = j * 16 + cl;
        const int gc = c0 + lc;
        const float d2 = sqr + sqB[lc] - 2.0f * acc[i][j][rg];
        const float dist = sqrtf(fmaxf(d2, 1e-12f));
        const u64 ph = ((u64)__float_as_uint(dist)) << 32;
        if (targets[gc] == tgt_r) {
          // argmax first-index tiebreak: larger (4095-gc) == smaller gc on ties
          u64 cand = ph | (unsigned)(4095 - gc);
          pm = pm > cand ? pm : cand;
        } else {
          u64 cand = ph | (unsigned)gc;
          nm = nm < cand ? nm : cand;
        }
      }
#pragma unroll
      for (int m = 1; m < 16; m <<= 1) {
        u64 pmo = __shfl_xor(pm, m, 64);
        u64 nmo = __shfl_xor(nm, m, 64);
        pm = pm > pmo ? pm : pmo;
        nm = nm < nmo ? nm : nmo;
      }
      if (cl == 0) {
        atomicMax(&posP[gr], pm);
        atomicMin(&negP[gr], nm);
      }
    }
  }

  // epilogue B: transposed mining (skip when the col-range lies inside the
  // row-range: cx in {2ry,2ry+1} -> both orderings already in row passes).
  if (cx >= 2 * ry + 2) {
#pragma unroll
    for (int j = 0; j < 4; ++j) {
      const int lc = j * 16 + cl;
      const int gc = c0 + lc;
      const int tgt_c = targets[gc];
      const float sqc = sqB[lc];
      u64 pm = 0ULL;
      u64 nm = ~0ULL;
#pragma unroll
      for (int i = 0; i < 2; ++i) {
#pragma unroll
        for (int rg = 0; rg < 4; ++rg) {
          const int lr = w * 32 + i * 16 + quad * 4 + rg;
          const int gr = r0 + lr;
          const float d2 = sqA[lr] + sqc - 2.0f * acc[i][j][rg];
          const float dist = sqrtf(fmaxf(d2, 1e-12f));
          const u64 ph = ((u64)__float_as_uint(dist)) << 32;
          if (targets[gr] == tgt_c) {
            u64 cand = ph | (unsigned)(4095 - gr);
            pm = pm > cand ? pm : cand;
          } else {
            u64 cand = ph | (unsigned)gr;
            nm = nm < cand ? nm : cand;
          }
        }
      }
#pragma unroll
      for (int m = 16; m < 64; m <<= 1) {
        u64 pmo = __shfl_xor(pm, m, 64);
        u64 nmo = __shfl_xor(nm, m, 64);
        pm = pm > pmo ? pm : pmo;
        nm = nm < nmo ? nm : nmo;
      }
      if (quad == 0) {
        atomicMax(&posP[gc], pm);
        atomicMin(&negP[gc], nm);
      }
    }
  }
}

// ---------------- local DTW + loss sums + fused finalize ----------------
__global__ __launch_bounds__(256) void local_dtw_kernel(
    const float* __restrict__ LF, const u64* __restrict__ posP,
    const u64* __restrict__ negP, float* __restrict__ sums,
    float* __restrict__ out) {
  __shared__ float bufA[4][1024];
  __shared__ float bufP[4][1024];
  __shared__ float bufN[4][1024];
  __shared__ float dmP[4][64];
  __shared__ float dmN[4][64];
  __shared__ float gterms[4], lterms[4];
  const int w = threadIdx.x >> 6, lane = threadIdx.x & 63;
  const int a = blockIdx.x * 4 + w;
  const u64 pp = posP[a];
  const u64 nn = negP[a];
  const int p_ind = 4095 - (int)(pp & 0xFFFFFFFFULL);
  const int n_ind = (int)(nn & 0xFFFFFFFFULL);
  const float dist_ap = __uint_as_float((unsigned)(pp >> 32));
  const float dist_an = __uint_as_float((unsigned)(nn >> 32));

  const float4* ga = (const float4*)(LF + (size_t)a * 1024);
  const float4* gp = (const float4*)(LF + (size_t)p_ind * 1024);
  const float4* gn = (const float4*)(LF + (size_t)n_ind * 1024);
  float4* la = (float4*)bufA[w];
  float4* lp = (float4*)bufP[w];
  float4* ln_ = (float4*)bufN[w];
#pragma unroll
  for (int i = 0; i < 4; ++i) {
    la[lane + i * 64] = ga[lane + i * 64];
    lp[lane + i * 64] = gp[lane + i * 64];
    ln_[lane + i * 64] = gn[lane + i * 64];
  }
  __syncthreads();
  const int t1 = lane >> 3, t2 = lane & 7;
  float sp = 0.f, sn = 0.f;
#pragma unroll 8
  for (int d = 0; d < 128; ++d) {
    float xa = bufA[w][d * 8 + t1];
    float xp = bufP[w][d * 8 + t2];
    float xn = bufN[w][d * 8 + t2];
    float e1 = xa - xp; sp += e1 * e1;
    float e2 = xa - xn; sn += e2 * e2;
  }
  dmP[w][lane] = tanhf(0.5f * sqrtf(fmaxf(sp, 1e-12f)));  // == (e^d-1)/(e^d+1)
  dmN[w][lane] = tanhf(0.5f * sqrtf(fmaxf(sn, 1e-12f)));
  __syncthreads();
  if (lane == 0) {
    float ap, an;
    {
      const float* dm = dmP[w];
      float row[8];
      row[0] = dm[0];
#pragma unroll
      for (int j = 1; j < 8; ++j) row[j] = row[j - 1] + dm[j];
#pragma unroll
      for (int i = 1; i < 8; ++i) {
        row[0] = row[0] + dm[i * 8];
#pragma unroll
        for (int j = 1; j < 8; ++j) row[j] = fminf(row[j], row[j - 1]) + dm[i * 8 + j];
      }
      ap = row[7];
    }
    {
      const float* dm = dmN[w];
      float row[8];
      row[0] = dm[0];
#pragma unroll
      for (int j = 1; j < 8; ++j) row[j] = row[j - 1] + dm[j];
#pragma unroll
      for (int i = 1; i < 8; ++i) {
        row[0] = row[0] + dm[i * 8];
#pragma unroll
        for (int j = 1; j < 8; ++j) row[j] = fminf(row[j], row[j - 1]) + dm[i * 8 + j];
      }
      an = row[7];
    }
    gterms[w] = fmaxf(dist_ap - dist_an + MARGINF, 0.f);
    lterms[w] = fmaxf(ap - an + MARGINF, 0.f);
  }
  __syncthreads();
  if (threadIdx.x == 0) {
    atomicAdd(&sums[0], gterms[0] + gterms[1] + gterms[2] + gterms[3]);
    atomicAdd(&sums[1], lterms[0] + lterms[1] + lterms[2] + lterms[3]);
    __threadfence();
    const unsigned done = atomicAdd((unsigned*)&sums[2], 1u);
    if (done == (unsigned)(gridDim.x - 1)) {
      const float g = atomicAdd(&sums[0], 0.f);
      const float l = atomicAdd(&sums[1], 0.f);
      out[0] = g * (1.0f / 4096.0f);
      out[1] = l * (1.0f / 4096.0f);
    }
  }
}

extern "C" void kernel_launch(void* const* d_in, const int* in_sizes, int n_in,
                              void* d_out, int out_size, void* d_ws, size_t ws_size,
                              hipStream_t stream) {
  const float* X = (const float*)d_in[0];
  const int* targets = (const int*)d_in[1];
  const float* LF = (const float*)d_in[2];
  float* out = (float*)d_out;

  char* ws = (char*)d_ws;
  size_t off = 0;
  u64* posP = (u64*)(ws + off); off += (size_t)NS * 8;
  u64* negP = (u64*)(ws + off); off += (size_t)NS * 8;
  float* sums = (float*)(ws + off); off += 256;

  hipMemsetAsync(posP, 0x00, (size_t)NS * 8, stream);   // max-init (dist >= 0)
  hipMemsetAsync(negP, 0xFF, (size_t)NS * 8, stream);   // min-init
  hipMemsetAsync(sums, 0x00, 16, stream);               // sums + done-counter

  gemm_mine_kernel<<<NBLK, 256, 0, stream>>>(X, targets, posP, negP);
  local_dtw_kernel<<<NS / 4, 256, 0, stream>>>(LF, posP, negP, sums, out);
}

// Round 13
// 192.492 us; speedup vs baseline: 2.7428x; 2.7428x over previous
//
#include <hip/hip_runtime.h>
#include <stdint.h>

#define NS 4096
#define DIM 2048
#define MARGINF 0.3f

typedef __bf16 bf16x8 __attribute__((ext_vector_type(8)));
typedef float floatx4 __attribute__((ext_vector_type(4)));

#define GLOBAL_AS __attribute__((address_space(1)))
#define LDS_AS __attribute__((address_space(3)))

__device__ __forceinline__ unsigned short f2bf_rne(float x) {
  unsigned u = __float_as_uint(x);
  u += 0x7FFFu + ((u >> 16) & 1u);
  return (unsigned short)(u >> 16);
}
__device__ __forceinline__ float bf2f(unsigned short b) {
  return __uint_as_float(((unsigned)b) << 16);
}

// ---------------- kernel 1: fp32 -> bf16 convert + row norms + init ----------------
__global__ __launch_bounds__(256) void prep_kernel(
    const float* __restrict__ X, unsigned short* __restrict__ Xbf,
    float* __restrict__ sq, unsigned long long* __restrict__ posP,
    unsigned long long* __restrict__ negP, float* __restrict__ sums) {
  const int row = blockIdx.x;
  const int t = threadIdx.x;
  const float4* xr = (const float4*)(X + (size_t)row * DIM);
  ushort4* br = (ushort4*)(Xbf + (size_t)row * DIM);
  float s = 0.f;
#pragma unroll
  for (int it = 0; it < 2; ++it) {
    int i = t + it * 256;
    float4 v = xr[i];
    ushort4 o;
    o.x = f2bf_rne(v.x); o.y = f2bf_rne(v.y);
    o.z = f2bf_rne(v.z); o.w = f2bf_rne(v.w);
    // norm of the ROUNDED values so d2 is consistent with the MFMA dot
    float b0 = bf2f(o.x), b1 = bf2f(o.y), b2 = bf2f(o.z), b3 = bf2f(o.w);
    s += b0 * b0 + b1 * b1 + b2 * b2 + b3 * b3;
    br[i] = o;
  }
#pragma unroll
  for (int m = 32; m > 0; m >>= 1) s += __shfl_down(s, m, 64);
  __shared__ float ls[4];
  const int w = t >> 6, lane = t & 63;
  if (lane == 0) ls[w] = s;
  __syncthreads();
  if (t == 0) {
    sq[row] = ls[0] + ls[1] + ls[2] + ls[3];
    posP[row] = 0ULL;
    negP[row] = ~0ULL;
    if (row == 0) { sums[0] = 0.f; sums[1] = 0.f; }
  }
}

// ---------------- kernel 2: fused Gram GEMM + mining, 128x64 tiles, 1056 blocks -----
// R8-proven config (76 µs): single 24 KB buffer, 1056 blocks = 4.1 queued/CU.
// Cross-block overlap is the latency-hiding mechanism (R9 LDS-dbuf and R12
// VGPR-dbuf both regressed: residency loss / scratch spills).
#define BM 128
#define BCN 64           // tile cols
#define BKE 64           // K elems staged per iter (128 B per row)
#define NBLK 1056

__device__ __forceinline__ void async16(const void* g, void* l) {
  __builtin_amdgcn_global_load_lds((GLOBAL_AS unsigned int*)g, (LDS_AS unsigned int*)l,
                                   16, 0, 0);
}

// tile id -> (ry, cx); cum(y) = y*(65-y) tiles precede row-chunk y; XCD swizzle 8x132
__device__ __forceinline__ void tile_decode(int tt, int& ry, int& cx) {
  const int t = (tt & 7) * 132 + (tt >> 3);
  int y = (int)((65.0f - sqrtf((float)(4225 - 4 * t))) * 0.5f);
  while ((y + 1) * (64 - y) <= t) ++y;   // cum(y+1) = (y+1)*(64-y)
  while (y * (65 - y) > t) --y;
  ry = y;
  cx = 2 * y + (t - y * (65 - y));
}

__global__ __launch_bounds__(256) void gemm_mine_kernel(
    const unsigned short* __restrict__ Xbf, const float* __restrict__ sq,
    const int* __restrict__ targets,
    unsigned long long* __restrict__ posP, unsigned long long* __restrict__ negP) {
  int ry, cx;
  tile_decode(blockIdx.x, ry, cx);
  const int r0 = ry * BM;
  const int c0 = cx * BCN;

  __shared__ __align__(16) unsigned short Ab[BM * BKE];   // 16 KB
  __shared__ __align__(16) unsigned short Bb[BCN * BKE];  //  8 KB
  const int tid = threadIdx.x;
  const int lane = tid & 63;
  const int w = tid >> 6;          // wave 0..3: rows w*32..w*32+31, all 64 cols
  const int quad = lane >> 4;
  const int ml = lane & 15;

  floatx4 acc[2][4];
#pragma unroll
  for (int i = 0; i < 2; ++i)
#pragma unroll
    for (int j = 0; j < 4; ++j)
#pragma unroll
      for (int k = 0; k < 4; ++k) acc[i][j][k] = 0.f;

  // staging (verified conflict-free): row = 8 chunks of 16 B; chunk c of row R at
  // slot c ^ (R&7); DMA lane -> (row lane>>3, slot lane&7) so lane fetches global
  // chunk (lane&7)^((lane>>3)&7). Each async16 = 8 rows x 128 B.
  const int r_rel = lane >> 3;
  const int c_g = (lane & 7) ^ r_rel;
  const unsigned short* gA = Xbf + (size_t)(r0 + w * 32 + r_rel) * DIM + c_g * 8;
  const unsigned short* gB = Xbf + (size_t)(c0 + w * 16 + r_rel) * DIM + c_g * 8;
  unsigned short* lA = Ab + w * 32 * BKE;   // wave stages A rows w*32..+31 (4 issues)
  unsigned short* lB = Bb + w * 16 * BKE;   // and B rows w*16..+15 (2 issues)
  const int sx = ml & 7;

  for (int k0 = 0; k0 < DIM; k0 += BKE) {
    __syncthreads();
#pragma unroll
    for (int q = 0; q < 4; ++q)
      async16(gA + (size_t)(q * 8) * DIM + k0, lA + q * 8 * BKE);
#pragma unroll
    for (int q = 0; q < 2; ++q)
      async16(gB + (size_t)(q * 8) * DIM + k0, lB + q * 8 * BKE);
    __syncthreads();   // vmcnt(0) drain
#pragma unroll
    for (int h = 0; h < 2; ++h) {
      const int slot = ((h << 2) + quad) ^ sx;
      bf16x8 af[2], bfr[4];
#pragma unroll
      for (int i = 0; i < 2; ++i)
        af[i] = *(const bf16x8*)(Ab + ((w * 32 + i * 16 + ml) * BKE) + slot * 8);
#pragma unroll
      for (int j = 0; j < 4; ++j)
        bfr[j] = *(const bf16x8*)(Bb + ((j * 16 + ml) * BKE) + slot * 8);
#pragma unroll
      for (int i = 0; i < 2; ++i)
#pragma unroll
        for (int j = 0; j < 4; ++j)
          acc[i][j] = __builtin_amdgcn_mfma_f32_16x16x32_bf16(af[i], bfr[j], acc[i][j], 0, 0, 0);
    }
  }

  // epilogue A: row-direction mining. C/D layout: col = lane&15, row = quad*4+reg.
  const int cl = ml;
#pragma unroll
  for (int i = 0; i < 2; ++i) {
#pragma unroll
    for (int rg = 0; rg < 4; ++rg) {
      const int gr = r0 + w * 32 + i * 16 + quad * 4 + rg;
      const int tgt_r = targets[gr];
      const float sqr = sq[gr];
      unsigned long long pm = 0ULL;
      unsigned long long nm = ~0ULL;
#pragma unroll
      for (int j = 0; j < 4; ++j) {
        const int gc = c0 + j * 16 + cl;
        const float d2 = sqr + sq[gc] - 2.0f * acc[i][j][rg];
        const float dist = sqrtf(fmaxf(d2, 1e-12f));
        const unsigned long long ph = ((unsigned long long)__float_as_uint(dist)) << 32;
        if (targets[gc] == tgt_r) {
          // argmax first-index tiebreak: larger (4095-gc) == smaller gc wins on ties
          unsigned long long cand = ph | (unsigned)(4095 - gc);
          pm = pm > cand ? pm : cand;
        } else {
          unsigned long long cand = ph | (unsigned)gc;
          nm = nm < cand ? nm : cand;
        }
      }
#pragma unroll
      for (int m = 1; m < 16; m <<= 1) {
        unsigned long long pmo = __shfl_xor(pm, m, 64);
        unsigned long long nmo = __shfl_xor(nm, m, 64);
        pm = pm > pmo ? pm : pmo;
        nm = nm < nmo ? nm : nmo;
      }
      if (cl == 0) {
        atomicMax(&posP[gr], pm);
        atomicMin(&negP[gr], nm);
      }
    }
  }

  // epilogue B: transposed mining (only when col-range is outside the row-range;
  // for cx in {2ry, 2ry+1} both orderings already appear in row passes).
  if (cx >= 2 * ry + 2) {
#pragma unroll
    for (int j = 0; j < 4; ++j) {
      const int gc = c0 + j * 16 + cl;
      const int tgt_c = targets[gc];
      const float sqc = sq[gc];
      unsigned long long pm = 0ULL;
      unsigned long long nm = ~0ULL;
#pragma unroll
      for (int i = 0; i < 2; ++i) {
#pragma unroll
        for (int rg = 0; rg < 4; ++rg) {
          const int gr = r0 + w * 32 + i * 16 + quad * 4 + rg;
          const float d2 = sq[gr] + sqc - 2.0f * acc[i][j][rg];
          const float dist = sqrtf(fmaxf(d2, 1e-12f));
          const unsigned long long ph = ((unsigned long long)__float_as_uint(dist)) << 32;
          if (targets[gr] == tgt_c) {
            unsigned long long cand = ph | (unsigned)(4095 - gr);
            pm = pm > cand ? pm : cand;
          } else {
            unsigned long long cand = ph | (unsigned)gr;
            nm = nm < cand ? nm : cand;
          }
        }
      }
#pragma unroll
      for (int m = 16; m < 64; m <<= 1) {
        unsigned long long pmo = __shfl_xor(pm, m, 64);
        unsigned long long nmo = __shfl_xor(nm, m, 64);
        pm = pm > pmo ? pm : pmo;
        nm = nm < nmo ? nm : nmo;
      }
      if (quad == 0) {
        atomicMax(&posP[gc], pm);
        atomicMin(&negP[gc], nm);
      }
    }
  }
}

// ---------------- kernel 3: local DTW distances + both loss sums ----------------
__global__ __launch_bounds__(256) void local_dtw_kernel(
    const float* __restrict__ LF, const unsigned long long* __restrict__ posP,
    const unsigned long long* __restrict__ negP, float* __restrict__ sums) {
  __shared__ float bufA[4][1024];
  __shared__ float bufP[4][1024];
  __shared__ float bufN[4][1024];
  __shared__ float dmP[4][64];
  __shared__ float dmN[4][64];
  __shared__ float gterms[4], lterms[4];
  const int w = threadIdx.x >> 6, lane = threadIdx.x & 63;
  const int a = blockIdx.x * 4 + w;
  const unsigned long long pp = posP[a];
  const unsigned long long nn = negP[a];
  const int p_ind = 4095 - (int)(pp & 0xFFFFFFFFULL);
  const int n_ind = (int)(nn & 0xFFFFFFFFULL);
  const float dist_ap = __uint_as_float((unsigned)(pp >> 32));
  const float dist_an = __uint_as_float((unsigned)(nn >> 32));

  const float4* ga = (const float4*)(LF + (size_t)a * 1024);
  const float4* gp = (const float4*)(LF + (size_t)p_ind * 1024);
  const float4* gn = (const float4*)(LF + (size_t)n_ind * 1024);
  float4* la = (float4*)bufA[w];
  float4* lp = (float4*)bufP[w];
  float4* ln_ = (float4*)bufN[w];
#pragma unroll
  for (int i = 0; i < 4; ++i) {
    la[lane + i * 64] = ga[lane + i * 64];
    lp[lane + i * 64] = gp[lane + i * 64];
    ln_[lane + i * 64] = gn[lane + i * 64];
  }
  __syncthreads();
  const int t1 = lane >> 3, t2 = lane & 7;
  float sp = 0.f, sn = 0.f;
#pragma unroll 8
  for (int d = 0; d < 128; ++d) {
    float xa = bufA[w][d * 8 + t1];
    float xp = bufP[w][d * 8 + t2];
    float xn = bufN[w][d * 8 + t2];
    float e1 = xa - xp; sp += e1 * e1;
    float e2 = xa - xn; sn += e2 * e2;
  }
  dmP[w][lane] = tanhf(0.5f * sqrtf(fmaxf(sp, 1e-12f)));  // == (e^d-1)/(e^d+1)
  dmN[w][lane] = tanhf(0.5f * sqrtf(fmaxf(sn, 1e-12f)));
  __syncthreads();
  // two serial 8x8 DPs per wave run concurrently on lanes 0 and 1
  if (lane < 2) {
    const float* dm = (lane == 0) ? dmP[w] : dmN[w];
    float row[8];
    row[0] = dm[0];
#pragma unroll
    for (int j = 1; j < 8; ++j) row[j] = row[j - 1] + dm[j];
#pragma unroll
    for (int i = 1; i < 8; ++i) {
      row[0] = row[0] + dm[i * 8];
#pragma unroll
      for (int j = 1; j < 8; ++j) row[j] = fminf(row[j], row[j - 1]) + dm[i * 8 + j];
    }
    if (lane == 0) dmP[w][0] = row[7];   // reuse LDS slot to pass ap
    else dmN[w][0] = row[7];             // an
  }
  __syncthreads();
  if (lane == 0) {
    gterms[w] = fmaxf(dist_ap - dist_an + MARGINF, 0.f);
    lterms[w] = fmaxf(dmP[w][0] - dmN[w][0] + MARGINF, 0.f);
  }
  __syncthreads();
  if (threadIdx.x == 0) {
    atomicAdd(&sums[0], gterms[0] + gterms[1] + gterms[2] + gterms[3]);
    atomicAdd(&sums[1], lterms[0] + lterms[1] + lterms[2] + lterms[3]);
  }
}

// ---------------- kernel 4: finalize ----------------
__global__ void finalize_kernel(const float* __restrict__ sums, float* __restrict__ out) {
  if (threadIdx.x == 0) {
    out[0] = sums[0] * (1.0f / 4096.0f);
    out[1] = sums[1] * (1.0f / 4096.0f);
  }
}

extern "C" void kernel_launch(void* const* d_in, const int* in_sizes, int n_in,
                              void* d_out, int out_size, void* d_ws, size_t ws_size,
                              hipStream_t stream) {
  const float* X = (const float*)d_in[0];
  const int* targets = (const int*)d_in[1];
  const float* LF = (const float*)d_in[2];
  float* out = (float*)d_out;

  char* ws = (char*)d_ws;
  size_t off = 0;
  unsigned short* Xbf = (unsigned short*)(ws + off); off += (size_t)NS * DIM * 2;  // 16 MB
  float* sq = (float*)(ws + off); off += (size_t)NS * 4;
  off = (off + 255) & ~(size_t)255;
  unsigned long long* posP = (unsigned long long*)(ws + off); off += (size_t)NS * 8;
  unsigned long long* negP = (unsigned long long*)(ws + off); off += (size_t)NS * 8;
  float* sums = (float*)(ws + off); off += 256;

  prep_kernel<<<NS, 256, 0, stream>>>(X, Xbf, sq, posP, negP, sums);
  gemm_mine_kernel<<<NBLK, 256, 0, stream>>>(Xbf, sq, targets, posP, negP);
  local_dtw_kernel<<<NS / 4, 256, 0, stream>>>(LF, posP, negP, sums);
  finalize_kernel<<<1, 64, 0, stream>>>(sums, out);
}